// Round 14
// baseline (222.595 us; speedup 1.0000x reference)
//
#include <hip/hip_runtime.h>

typedef __bf16 bf16_t;
typedef __bf16 bf16x4 __attribute__((ext_vector_type(4)));
typedef __bf16 bf16x8 __attribute__((ext_vector_type(8)));
typedef float floatx4 __attribute__((ext_vector_type(4)));
typedef signed char i8_t;
typedef int intx4 __attribute__((ext_vector_type(4)));

__device__ inline void split_hl(float v, bf16_t& hi, bf16_t& lo) {
    hi = (bf16_t)v;
    lo = (bf16_t)(v - (float)hi);
}

// ---------------- kernel 1: transpose + hi/lo split W ----------------
__global__ void wtrans_kernel(const float* __restrict__ W1,
                              const float* __restrict__ W2,
                              const float* __restrict__ W3,
                              bf16_t* __restrict__ Wthi, bf16_t* __restrict__ Wtlo) {
    __shared__ float T[64 * 68];
    const int zi = blockIdx.z;
    const float* W = (zi == 0) ? W1 : ((zi == 1) ? W2 : W3);
    bf16_t* ohi = Wthi + zi * 256 * 256;
    bf16_t* olo = Wtlo + zi * 256 * 256;
    const int c0 = blockIdx.x * 64, d0 = blockIdx.y * 64;
    const int tid = threadIdx.x;
#pragma unroll
    for (int i = 0; i < 4; i++) {
        int idx = i * 256 + tid;
        int r = idx >> 4, c4 = (idx & 15) * 4;
        floatx4 v = *(const floatx4*)(W + (c0 + r) * 256 + d0 + c4);
        *(floatx4*)(&T[r * 68 + c4]) = v;
    }
    __syncthreads();
#pragma unroll
    for (int i = 0; i < 4; i++) {
        int idx = i * 256 + tid;
        int rd = idx & 63, cc4 = (idx >> 6) * 4;
        bf16x4 vh, vl;
#pragma unroll
        for (int ii = 0; ii < 4; ii++) {
            float v = T[(cc4 + ii) * 68 + rd];
            bf16_t h, l; split_hl(v, h, l);
            vh[ii] = h; vl[ii] = l;
        }
        *(bf16x4*)(ohi + (d0 + rd) * 256 + c0 + cc4) = vh;
        *(bf16x4*)(olo + (d0 + rd) * 256 + c0 + cc4) = vl;
    }
}

// ---------------- kernel 2: fused [adjbits + projections] ----------------
// Round-14: W consumed STRAIGHT FROM GLOBAL (Wt is [d][c]-major -> a wave's
// B-fragment is a direct 16-B load per lane; L2-hot, same L2 bytes as staging).
// X double-buffered LDS + reg-prefetch, 1 barrier/step (round-13-verified
// structure). LDS ops/step 34 -> 12, barriers 2 -> 1, LDS 51.7 -> 34.9 KB.
__global__ __launch_bounds__(256) void projadj_kernel(
    const float* __restrict__ X,
    const bf16_t* __restrict__ Wthi, const bf16_t* __restrict__ Wtlo,
    i8_t* __restrict__ Q8h, i8_t* __restrict__ Q8l, float* __restrict__ sqv,
    i8_t* __restrict__ K8h, i8_t* __restrict__ K8l, float* __restrict__ skv,
    bf16_t* __restrict__ H3t,
    const int* __restrict__ adj, unsigned* __restrict__ bits) {
    __shared__ __align__(16) char SM[34816];
    // K-loop: X dbuf at SM + buf*10240 (Xh 5120 | Xl 5120); amS at SM+20480.
    // z=2 epilogue: VtB = SM (256*136 = 34816 B), after a barrier.
    float* amS = (float*)(SM + 20480);      // 512 B: [2][64]

    const int tid = threadIdx.x;
    const int blk = blockIdx.x;
    if (blk < 512) {
        int id = blk * 256 + tid;
        const int* p = adj + (size_t)id * 32;
        unsigned wbits = 0;
#pragma unroll
        for (int j = 0; j < 32; j += 4) {
            int4 v = *(const int4*)(p + j);
            wbits |= (v.x > 0 ? 1u : 0u) << j;
            wbits |= (v.y > 0 ? 1u : 0u) << (j + 1);
            wbits |= (v.z > 0 ? 1u : 0u) << (j + 2);
            wbits |= (v.w > 0 ? 1u : 0u) << (j + 3);
        }
        bits[id] = wbits;
        return;
    }

    const int pblk = blk - 512;
    const int z = pblk >> 8;
    const int row0 = (pblk & 255) * 64;
    const int w = tid >> 6, lane = tid & 63;
    const int m = lane & 15, q = lane >> 4;
    const int wr = w >> 1, wc = w & 1;

    // per-lane W fragment bases (global, [d][c]-major): row = wc*128 + ct*16 + m
    const bf16_t* wbh = Wthi + (size_t)z * 256 * 256 + (wc * 128 + m) * 256 + q * 8;
    const bf16_t* wbl = Wtlo + (size_t)z * 256 * 256 + (wc * 128 + m) * 256 + q * 8;

    // X staging regs (idx -> row r = idx>>3, col4 c4 = (idx&7)*4)
    const int xr_r[2] = { (0 * 256 + tid) >> 3, (1 * 256 + tid) >> 3 };
    const int xr_c4 = (tid & 7) * 4;
    floatx4 xr[2];
#pragma unroll
    for (int i = 0; i < 2; i++)
        xr[i] = *(const floatx4*)(X + (size_t)(row0 + xr_r[i]) * 256 + 0 + xr_c4);

    floatx4 acc[16];
#pragma unroll
    for (int i = 0; i < 16; i++) acc[i] = (floatx4){0.f, 0.f, 0.f, 0.f};

    int buf = 0;
    for (int c0 = 0; c0 < 256; c0 += 32, buf ^= 1) {
        bf16_t* Xh = (bf16_t*)(SM + buf * 10240);
        bf16_t* Xl = Xh + 2560;
        // write staged regs -> LDS buf (prev reads of this buf separated by barrier)
#pragma unroll
        for (int i = 0; i < 2; i++) {
            bf16x4 vh, vl;
#pragma unroll
            for (int ii = 0; ii < 4; ii++) {
                bf16_t h, l; split_hl(xr[i][ii], h, l);
                vh[ii] = h; vl[ii] = l;
            }
            *(bf16x4*)(&Xh[xr_r[i] * 40 + xr_c4]) = vh;
            *(bf16x4*)(&Xl[xr_r[i] * 40 + xr_c4]) = vl;
        }
        __syncthreads();   // the ONLY barrier per step
        if (c0 + 32 < 256) {   // prefetch next X cols while computing
#pragma unroll
            for (int i = 0; i < 2; i++)
                xr[i] = *(const floatx4*)(X + (size_t)(row0 + xr_r[i]) * 256 + c0 + 32 + xr_c4);
        }
        bf16x8 ah[2], al[2];
#pragma unroll
        for (int rt = 0; rt < 2; rt++) {
            ah[rt] = *(const bf16x8*)(&Xh[(wr * 32 + rt * 16 + m) * 40 + q * 8]);
            al[rt] = *(const bf16x8*)(&Xl[(wr * 32 + rt * 16 + m) * 40 + q * 8]);
        }
#pragma unroll
        for (int ct = 0; ct < 8; ct++) {
            bf16x8 bh = *(const bf16x8*)(wbh + (size_t)(ct * 16) * 256 + c0);
            bf16x8 bl = *(const bf16x8*)(wbl + (size_t)(ct * 16) * 256 + c0);
#pragma unroll
            for (int rt = 0; rt < 2; rt++) {
                acc[rt * 8 + ct] = __builtin_amdgcn_mfma_f32_16x16x32_bf16(ah[rt], bh, acc[rt * 8 + ct], 0, 0, 0);
                acc[rt * 8 + ct] = __builtin_amdgcn_mfma_f32_16x16x32_bf16(ah[rt], bl, acc[rt * 8 + ct], 0, 0, 0);
                acc[rt * 8 + ct] = __builtin_amdgcn_mfma_f32_16x16x32_bf16(al[rt], bh, acc[rt * 8 + ct], 0, 0, 0);
            }
        }
    }

    if (z < 2) {
        i8_t* Dh = (z == 0) ? Q8h : K8h;
        i8_t* Dl = (z == 0) ? Q8l : K8l;
        float* sv = (z == 0) ? sqv : skv;
        float am[2][4];
#pragma unroll
        for (int rt = 0; rt < 2; rt++)
#pragma unroll
            for (int r = 0; r < 4; r++) am[rt][r] = 0.f;
#pragma unroll
        for (int ct = 0; ct < 8; ct++)
#pragma unroll
            for (int rt = 0; rt < 2; rt++)
#pragma unroll
                for (int r = 0; r < 4; r++)
                    am[rt][r] = fmaxf(am[rt][r], fabsf(acc[rt * 8 + ct][r]));
#pragma unroll
        for (int off = 1; off < 16; off <<= 1)
#pragma unroll
            for (int rt = 0; rt < 2; rt++)
#pragma unroll
                for (int r = 0; r < 4; r++)
                    am[rt][r] = fmaxf(am[rt][r], __shfl_xor(am[rt][r], off, 64));
        if (m == 0) {
#pragma unroll
            for (int rt = 0; rt < 2; rt++)
#pragma unroll
                for (int r = 0; r < 4; r++)
                    amS[wc * 64 + wr * 32 + rt * 16 + q * 4 + r] = am[rt][r];
        }
        __syncthreads();
        float sc[2][4], inv[2][4];
#pragma unroll
        for (int rt = 0; rt < 2; rt++)
#pragma unroll
            for (int r = 0; r < 4; r++) {
                int row = wr * 32 + rt * 16 + q * 4 + r;
                float a = fmaxf(amS[row], amS[64 + row]);
                sc[rt][r]  = (a > 0.f) ? a * (1.f / 127.f) : 1.f;
                inv[rt][r] = (a > 0.f) ? 127.f / a : 0.f;
            }
#pragma unroll
        for (int ct = 0; ct < 8; ct++)
#pragma unroll
            for (int rt = 0; rt < 2; rt++)
#pragma unroll
                for (int r = 0; r < 4; r++) {
                    float vq = acc[rt * 8 + ct][r] * inv[rt][r];
                    float qh = rintf(vq);
                    float ql = fminf(fmaxf(rintf((vq - qh) * 256.f), -127.f), 127.f);
                    int offo = (row0 + wr * 32 + rt * 16 + q * 4 + r) * 256 +
                               wc * 128 + ct * 16 + m;
                    Dh[offo] = (i8_t)(int)qh;
                    Dl[offo] = (i8_t)(int)ql;
                }
        if (m == 0 && wc == 0) {
#pragma unroll
            for (int rt = 0; rt < 2; rt++)
#pragma unroll
                for (int r = 0; r < 4; r++)
                    sv[row0 + wr * 32 + rt * 16 + q * 4 + r] = sc[rt][r];
        }
    } else {
        __syncthreads();   // all waves done with X LDS before VtB overwrite
        char* VtB = SM;    // 256*136 = 34816 B
#pragma unroll
        for (int ct = 0; ct < 8; ct++)
#pragma unroll
            for (int rt = 0; rt < 2; rt++) {
                int d = wc * 128 + ct * 16 + m;
                int n0 = wr * 32 + rt * 16 + q * 4;
                bf16x4 v4;
#pragma unroll
                for (int r = 0; r < 4; r++) v4[r] = (bf16_t)acc[rt * 8 + ct][r];
                *(bf16x4*)(VtB + d * 136 + n0 * 2) = v4;
            }
        __syncthreads();
        const int bb = row0 >> 11;
        const int nbase = row0 & 2047;
        bf16_t* Hrow = H3t + (size_t)bb * 256 * 2048 + nbase;
#pragma unroll
        for (int it = 0; it < 16; it++) {
            int d = it * 16 + (tid >> 4);
            int c8 = tid & 15;
            bf16x4 v = *(const bf16x4*)(VtB + d * 136 + c8 * 8);
            *(bf16x4*)(Hrow + (size_t)d * 2048 + c8 * 4) = v;
        }
    }
}

// ---------------- kernel 3: flash attention (1-barrier dbuf + s_setprio) ----------------
// Round-13 win locked (1 barrier/tile, dbuf K/V, attn 99 us). NEW: s_setprio(1)
// around the QK and PV MFMA clusters (T5) -- register-neutral; the staggered
// 1-barrier pipeline + 2 independent blocks/CU gives the scheduler a role-split.
#define K8SW(row, off) ((off) ^ (((row) & 7) << 4))        // K8 row stride 256B
#define VSW(row, off)  ((off) ^ ((((row) >> 1) & 3) << 4)) // Vl/Pl row stride 64B
__global__ __launch_bounds__(256, 2) void attn_kernel(
    const i8_t* __restrict__ Q8h, const i8_t* __restrict__ Q8l,
    const float* __restrict__ sqv,
    const i8_t* __restrict__ K8h, const i8_t* __restrict__ K8l,
    const float* __restrict__ skv,
    const bf16_t* __restrict__ H3t, const unsigned* __restrict__ adjbits,
    bf16_t* __restrict__ Opart, float* __restrict__ mpart, float* __restrict__ lpart,
    int klen) {
    __shared__ i8_t K8[2][2][32 * 256];   // [buf][hi/lo] (32 KB)
    __shared__ bf16_t Vl[2][256 * 32];    // [buf] (32 KB)
    __shared__ bf16_t Pl[4][16 * 32];     // per-wave P round-trip (4 KB)

    const int nwg = (int)(gridDim.x * gridDim.y * gridDim.z);   // 32*8*S
    const int wgid = (int)(blockIdx.x + (blockIdx.y << 5) + (blockIdx.z << 8));
    const int nid = (wgid & 7) * (nwg >> 3) + (wgid >> 3);
    const int qb = nid & 31;
    const int b  = (nid >> 5) & 7;
    const int kz = nid >> 8;

    const int q0 = qb * 64;
    const int tid = threadIdx.x;
    const int w = tid >> 6, lane = tid & 63;
    const int m = lane & 15, q = lane >> 4;

    char* PlB = (char*)&Pl[w][0];

    const i8_t* qrh = Q8h + (size_t)(b * 2048 + q0 + w * 16 + m) * 256;
    const i8_t* qrl = Q8l + (size_t)(b * 2048 + q0 + w * 16 + m) * 256;
    intx4 qh8[4], ql8[4];
#pragma unroll
    for (int ck = 0; ck < 4; ck++) {
        qh8[ck] = *(const intx4*)(qrh + ck * 64 + q * 16);
        ql8[ck] = *(const intx4*)(qrl + ck * 64 + q * 16);
    }
    float sq4[4];
#pragma unroll
    for (int r = 0; r < 4; r++) sq4[r] = sqv[b * 2048 + q0 + w * 16 + q * 4 + r];

    bf16x8 vones;
#pragma unroll
    for (int i = 0; i < 8; i++) vones[i] = (bf16_t)1.0f;

    float m_run[4];
#pragma unroll
    for (int r = 0; r < 4; r++) m_run[r] = -3.0e38f;
    floatx4 l_acc = (floatx4){0.f, 0.f, 0.f, 0.f};
    floatx4 o[16];
#pragma unroll
    for (int i = 0; i < 16; i++) o[i] = (floatx4){0.f, 0.f, 0.f, 0.f};

    const unsigned* bitrow[4];
#pragma unroll
    for (int r = 0; r < 4; r++)
        bitrow[r] = adjbits + (size_t)(q0 + w * 16 + q * 4 + r) * 64;

    intx4 rkh[2], rkl[2];
    bf16x8 rvv[4];
    float skt[2], skn[2];
    const int kbeg = kz * klen, kend = kbeg + klen;

#pragma unroll
    for (int i = 0; i < 2; i++) {
        int ci = i * 256 + tid;
        int kr = ci >> 4, cb = (ci & 15) * 16;
        rkh[i] = *(const intx4*)(K8h + (size_t)(b * 2048 + kbeg + kr) * 256 + cb);
        rkl[i] = *(const intx4*)(K8l + (size_t)(b * 2048 + kbeg + kr) * 256 + cb);
    }
#pragma unroll
    for (int i = 0; i < 4; i++) {
        int ci = i * 256 + tid;
        int d = ci >> 2, k8 = (ci & 3) * 8;
        rvv[i] = *(const bf16x8*)(H3t + (size_t)(b * 256 + d) * 2048 + kbeg + k8);
    }
    skt[0] = skv[b * 2048 + kbeg + m];
    skt[1] = skv[b * 2048 + kbeg + 16 + m];

    int kbuf = 0;
    for (int k0 = kbeg; k0 < kend; k0 += 32) {
        char* KB0 = (char*)&K8[kbuf][0][0];
        char* KB1 = (char*)&K8[kbuf][1][0];
        char* VB  = (char*)&Vl[kbuf][0];
#pragma unroll
        for (int i = 0; i < 2; i++) {
            int ci = i * 256 + tid;
            int kr = ci >> 4, cb = (ci & 15) * 16;
            *(intx4*)(KB0 + K8SW(kr, kr * 256 + cb)) = rkh[i];
            *(intx4*)(KB1 + K8SW(kr, kr * 256 + cb)) = rkl[i];
        }
#pragma unroll
        for (int i = 0; i < 4; i++) {
            int ci = i * 256 + tid;
            int d = ci >> 2, kb = (ci & 3) * 16;
            *(bf16x8*)(VB + VSW(d, d * 64 + kb)) = rvv[i];
        }
        __syncthreads();   // the ONLY barrier per tile

        if (k0 + 32 < kend) {
            int kn = k0 + 32;
#pragma unroll
            for (int i = 0; i < 2; i++) {
                int ci = i * 256 + tid;
                int kr = ci >> 4, cb = (ci & 15) * 16;
                rkh[i] = *(const intx4*)(K8h + (size_t)(b * 2048 + kn + kr) * 256 + cb);
                rkl[i] = *(const intx4*)(K8l + (size_t)(b * 2048 + kn + kr) * 256 + cb);
            }
#pragma unroll
            for (int i = 0; i < 4; i++) {
                int ci = i * 256 + tid;
                int d = ci >> 2, k8 = (ci & 3) * 8;
                rvv[i] = *(const bf16x8*)(H3t + (size_t)(b * 256 + d) * 2048 + kn + k8);
            }
            skn[0] = skv[b * 2048 + kn + m];
            skn[1] = skv[b * 2048 + kn + 16 + m];
        }

        // ---- S = Q K^T in i8 hi/lo ----
        float s[2][4];
        __builtin_amdgcn_s_setprio(1);
#pragma unroll
        for (int t = 0; t < 2; t++) {
            intx4 ch = {0, 0, 0, 0}, cm = {0, 0, 0, 0};
            const int row = t * 16 + m;
#pragma unroll
            for (int ck = 0; ck < 4; ck++) {
                const int cb2 = ck * 64 + q * 16;
                intx4 kh = *(const intx4*)(KB0 + K8SW(row, row * 256 + cb2));
                intx4 kl = *(const intx4*)(KB1 + K8SW(row, row * 256 + cb2));
                ch = __builtin_amdgcn_mfma_i32_16x16x64_i8(qh8[ck], kh, ch, 0, 0, 0);
                cm = __builtin_amdgcn_mfma_i32_16x16x64_i8(qh8[ck], kl, cm, 0, 0, 0);
                cm = __builtin_amdgcn_mfma_i32_16x16x64_i8(ql8[ck], kh, cm, 0, 0, 0);
            }
#pragma unroll
            for (int r = 0; r < 4; r++)
                s[t][r] = fmaf((float)cm[r], 0.00390625f, (float)ch[r]) * (sq4[r] * skt[t]);
        }
        __builtin_amdgcn_s_setprio(0);

        // ---- leaky-relu + mask + tile row max ----
        unsigned aw[4];
#pragma unroll
        for (int r = 0; r < 4; r++) aw[r] = bitrow[r][k0 >> 5];
        float p[2][4], tmax[4];
#pragma unroll
        for (int r = 0; r < 4; r++) tmax[r] = -3.0e38f;
#pragma unroll
        for (int t = 0; t < 2; t++)
#pragma unroll
            for (int r = 0; r < 4; r++) {
                float v = s[t][r];
                v = (v > 0.f) ? v : 0.2f * v;
                v = ((aw[r] >> (t * 16 + m)) & 1u) ? v : -1.0e12f;
                p[t][r] = v;
                tmax[r] = fmaxf(tmax[r], v);
            }
#pragma unroll
        for (int off = 1; off < 16; off <<= 1)
#pragma unroll
            for (int r = 0; r < 4; r++)
                tmax[r] = fmaxf(tmax[r], __shfl_xor(tmax[r], off, 64));

        // ---- defer-max (THR=8) ----
        int rise = 0;
#pragma unroll
        for (int r = 0; r < 4; r++)
            rise |= (tmax[r] > m_run[r] + 8.f);
        if (__any(rise)) {
#pragma unroll
            for (int r = 0; r < 4; r++) {
                float mnew = fmaxf(m_run[r], tmax[r]);
                float alpha = __expf(m_run[r] - mnew);
                m_run[r] = mnew;
                l_acc[r] *= alpha;
#pragma unroll
                for (int nt = 0; nt < 16; nt++) o[nt][r] *= alpha;
            }
        }
#pragma unroll
        for (int t = 0; t < 2; t++)
#pragma unroll
            for (int r = 0; r < 4; r++)
                p[t][r] = __expf(p[t][r] - m_run[r]);

        // ---- P: C-layout -> per-wave LDS -> A-layout (same wave, no barrier) ----
#pragma unroll
        for (int t = 0; t < 2; t++)
#pragma unroll
            for (int r = 0; r < 4; r++) {
                int row = q * 4 + r;
                *(bf16_t*)(PlB + VSW(row, row * 64 + (t * 16 + m) * 2)) = (bf16_t)p[t][r];
            }
        bf16x8 pf = *(const bf16x8*)(PlB + VSW(m, m * 64 + q * 16));

        // ---- l += P @ ones; O += P @ V ----
        __builtin_amdgcn_s_setprio(1);
        l_acc = __builtin_amdgcn_mfma_f32_16x16x32_bf16(pf, vones, l_acc, 0, 0, 0);
#pragma unroll
        for (int nt = 0; nt < 16; nt++) {
            const int vr = nt * 16 + m;
            bf16x8 vf = *(const bf16x8*)(VB + VSW(vr, vr * 64 + q * 16));
            o[nt] = __builtin_amdgcn_mfma_f32_16x16x32_bf16(pf, vf, o[nt], 0, 0, 0);
        }
        __builtin_amdgcn_s_setprio(0);
        skt[0] = skn[0];
        skt[1] = skn[1];
        kbuf ^= 1;
    }

    const int rowg = kz * 16384 + b * 2048 + q0 + w * 16 + q * 4;
#pragma unroll
    for (int nt = 0; nt < 16; nt++)
#pragma unroll
        for (int r = 0; r < 4; r++)
            Opart[(size_t)(rowg + r) * 256 + nt * 16 + m] = (bf16_t)o[nt][r];
    if (m == 0) {
#pragma unroll
        for (int r = 0; r < 4; r++) {
            mpart[rowg + r] = m_run[r];
            lpart[rowg + r] = l_acc[r];
        }
    }
}

// ---------------- kernel 4: merge splits + normalize + relu ----------------
__global__ __launch_bounds__(256) void merge_kernel(
    const bf16_t* __restrict__ Opart, const float* __restrict__ mpart,
    const float* __restrict__ lpart, float* __restrict__ out, int S) {
    int gid = blockIdx.x * 256 + threadIdx.x;
    int row = gid >> 6, c4 = (gid & 63) * 4;
    float M = -3.0e38f;
    for (int s = 0; s < S; s++) M = fmaxf(M, mpart[s * 16384 + row]);
    float denom = 0.f;
    float4 acc = make_float4(0.f, 0.f, 0.f, 0.f);
    for (int s = 0; s < S; s++) {
        float sc = __expf(mpart[s * 16384 + row] - M);
        denom += lpart[s * 16384 + row] * sc;
        bf16x4 v = *(const bf16x4*)(Opart + ((size_t)(s * 16384 + row)) * 256 + c4);
        acc.x += (float)v[0] * sc; acc.y += (float)v[1] * sc;
        acc.z += (float)v[2] * sc; acc.w += (float)v[3] * sc;
    }
    float inv = 1.f / denom;
    float4 r;
    r.x = fmaxf(acc.x * inv, 0.f);
    r.y = fmaxf(acc.y * inv, 0.f);
    r.z = fmaxf(acc.z * inv, 0.f);
    r.w = fmaxf(acc.w * inv, 0.f);
    *(float4*)(out + (size_t)row * 256 + c4) = r;
}

extern "C" void kernel_launch(void* const* d_in, const int* in_sizes, int n_in,
                              void* d_out, int out_size, void* d_ws, size_t ws_size,
                              hipStream_t stream) {
    const float* X   = (const float*)d_in[0];
    const int*   adj = (const int*)d_in[1];
    const float* W1  = (const float*)d_in[2];
    const float* W2  = (const float*)d_in[3];
    const float* W3  = (const float*)d_in[4];
    float* out = (float*)d_out;

    char* ws = (char*)d_ws;
    i8_t* Q8h = (i8_t*)(ws + ((size_t)0 << 20));    // 16384*256 = 4 MB each
    i8_t* Q8l = (i8_t*)(ws + ((size_t)4 << 20));
    i8_t* K8h = (i8_t*)(ws + ((size_t)8 << 20));
    i8_t* K8l = (i8_t*)(ws + ((size_t)12 << 20));
    bf16_t* H3t = (bf16_t*)(ws + ((size_t)16 << 20));   // 8 MB
    float* sqv = (float*)(ws + ((size_t)24 << 20));     // 64 KB
    float* skv = (float*)(ws + ((size_t)24 << 20) + 65536);
    size_t wt0 = ((size_t)24 << 20) + 131072;
    bf16_t* Wthi = (bf16_t*)(ws + wt0);                 // 393,216 B
    bf16_t* Wtlo = (bf16_t*)(ws + wt0 + 393216);        // 393,216 B
    float* mpart = (float*)(ws + wt0);                  // overlays Wt (dead after proj)
    float* lpart = (float*)(ws + wt0 + 131072);
    unsigned* adjb = (unsigned*)(ws + wt0 + 786432);    // 524,288 B
    size_t opart_off = wt0 + 786432 + 524288;
    const size_t need2 = opart_off + (size_t)2 * 16384 * 256 * 2;  // bf16 Opart, ~43 MB

    int S = (ws_size >= need2) ? 2 : 1;
    bf16_t* Opart = (bf16_t*)(ws + opart_off);

    wtrans_kernel<<<dim3(4, 4, 3), 256, 0, stream>>>(W1, W2, W3, Wthi, Wtlo);
    projadj_kernel<<<1280, 256, 0, stream>>>(X, Wthi, Wtlo,
                                             Q8h, Q8l, sqv, K8h, K8l, skv, H3t,
                                             adj, adjb);
    attn_kernel<<<dim3(32, 8, S), 256, 0, stream>>>(Q8h, Q8l, sqv, K8h, K8l, skv,
                                                    H3t, adjb, Opart, mpart, lpart,
                                                    2048 / S);
    merge_kernel<<<4096, 256, 0, stream>>>(Opart, mpart, lpart, out, S);
}

// Round 15
// 202.372 us; speedup vs baseline: 1.0999x; 1.0999x over previous
//
#include <hip/hip_runtime.h>

typedef __bf16 bf16_t;
typedef __bf16 bf16x4 __attribute__((ext_vector_type(4)));
typedef __bf16 bf16x8 __attribute__((ext_vector_type(8)));
typedef float floatx4 __attribute__((ext_vector_type(4)));
typedef signed char i8_t;
typedef int intx4 __attribute__((ext_vector_type(4)));

__device__ inline void split_hl(float v, bf16_t& hi, bf16_t& lo) {
    hi = (bf16_t)v;
    lo = (bf16_t)(v - (float)hi);
}

// ---------------- kernel 1: transpose + hi/lo split W ----------------
__global__ void wtrans_kernel(const float* __restrict__ W1,
                              const float* __restrict__ W2,
                              const float* __restrict__ W3,
                              bf16_t* __restrict__ Wthi, bf16_t* __restrict__ Wtlo) {
    __shared__ float T[64 * 68];
    const int zi = blockIdx.z;
    const float* W = (zi == 0) ? W1 : ((zi == 1) ? W2 : W3);
    bf16_t* ohi = Wthi + zi * 256 * 256;
    bf16_t* olo = Wtlo + zi * 256 * 256;
    const int c0 = blockIdx.x * 64, d0 = blockIdx.y * 64;
    const int tid = threadIdx.x;
#pragma unroll
    for (int i = 0; i < 4; i++) {
        int idx = i * 256 + tid;
        int r = idx >> 4, c4 = (idx & 15) * 4;
        floatx4 v = *(const floatx4*)(W + (c0 + r) * 256 + d0 + c4);
        *(floatx4*)(&T[r * 68 + c4]) = v;
    }
    __syncthreads();
#pragma unroll
    for (int i = 0; i < 4; i++) {
        int idx = i * 256 + tid;
        int rd = idx & 63, cc4 = (idx >> 6) * 4;
        bf16x4 vh, vl;
#pragma unroll
        for (int ii = 0; ii < 4; ii++) {
            float v = T[(cc4 + ii) * 68 + rd];
            bf16_t h, l; split_hl(v, h, l);
            vh[ii] = h; vl[ii] = l;
        }
        *(bf16x4*)(ohi + (d0 + rd) * 256 + c0 + cc4) = vh;
        *(bf16x4*)(olo + (d0 + rd) * 256 + c0 + cc4) = vl;
    }
}

// ---------------- kernel 2: fused [adjbits + projections] (round-13 version) ----------------
// REVERTED from round-14's W-from-global (regressed ~19 us: 64-lane 16B loads at
// 512-B stride = 32 lines/instr, repeated 16x/step with no reuse capture; LDS
// staging is what made W bytes cheap). This is the measured-good round-13 proj:
// 2x2 wave-tiling + LDS-staged W + coalesced V^T epilogue + fused adjbits.
__global__ __launch_bounds__(256) void projadj_kernel(
    const float* __restrict__ X,
    const bf16_t* __restrict__ Wthi, const bf16_t* __restrict__ Wtlo,
    i8_t* __restrict__ Q8h, i8_t* __restrict__ Q8l, float* __restrict__ sqv,
    i8_t* __restrict__ K8h, i8_t* __restrict__ K8l, float* __restrict__ skv,
    bf16_t* __restrict__ H3t,
    const int* __restrict__ adj, unsigned* __restrict__ bits) {
    __shared__ __align__(16) char SM[51712];
    bf16_t* Xh = (bf16_t*)(SM);             //  5120 B: [64][40]
    bf16_t* Xl = (bf16_t*)(SM + 5120);      //  5120 B
    bf16_t* Wh = (bf16_t*)(SM + 10240);     // 20480 B: [256][40]
    bf16_t* Wl = (bf16_t*)(SM + 30720);     // 20480 B
    float* amS = (float*)(SM + 51200);      //   512 B: [2][64]

    const int tid = threadIdx.x;
    const int blk = blockIdx.x;
    if (blk < 512) {
        int id = blk * 256 + tid;
        const int* p = adj + (size_t)id * 32;
        unsigned wbits = 0;
#pragma unroll
        for (int j = 0; j < 32; j += 4) {
            int4 v = *(const int4*)(p + j);
            wbits |= (v.x > 0 ? 1u : 0u) << j;
            wbits |= (v.y > 0 ? 1u : 0u) << (j + 1);
            wbits |= (v.z > 0 ? 1u : 0u) << (j + 2);
            wbits |= (v.w > 0 ? 1u : 0u) << (j + 3);
        }
        bits[id] = wbits;
        return;
    }

    const int pblk = blk - 512;
    const int z = pblk >> 8;
    const int row0 = (pblk & 255) * 64;
    const int w = tid >> 6, lane = tid & 63;
    const int m = lane & 15, q = lane >> 4;
    const int wr = w >> 1, wc = w & 1;
    const bf16_t* Wzh = Wthi + z * 256 * 256;
    const bf16_t* Wzl = Wtlo + z * 256 * 256;

    floatx4 acc[16];
#pragma unroll
    for (int i = 0; i < 16; i++) acc[i] = (floatx4){0.f, 0.f, 0.f, 0.f};

    for (int c0 = 0; c0 < 256; c0 += 32) {
#pragma unroll
        for (int i = 0; i < 2; i++) {
            int idx = i * 256 + tid;
            int r = idx >> 3, c4 = (idx & 7) * 4;
            floatx4 v = *(const floatx4*)(X + (size_t)(row0 + r) * 256 + c0 + c4);
            bf16x4 vh, vl;
#pragma unroll
            for (int ii = 0; ii < 4; ii++) {
                bf16_t h, l; split_hl(v[ii], h, l);
                vh[ii] = h; vl[ii] = l;
            }
            *(bf16x4*)(&Xh[r * 40 + c4]) = vh;
            *(bf16x4*)(&Xl[r * 40 + c4]) = vl;
        }
#pragma unroll
        for (int i = 0; i < 4; i++) {
            int idx = i * 256 + tid;
            int d = idx >> 2, c8 = (idx & 3) * 8;
            *(bf16x8*)(&Wh[d * 40 + c8]) = *(const bf16x8*)(Wzh + d * 256 + c0 + c8);
            *(bf16x8*)(&Wl[d * 40 + c8]) = *(const bf16x8*)(Wzl + d * 256 + c0 + c8);
        }
        __syncthreads();
        bf16x8 ah[2], al[2];
#pragma unroll
        for (int rt = 0; rt < 2; rt++) {
            ah[rt] = *(const bf16x8*)(&Xh[(wr * 32 + rt * 16 + m) * 40 + q * 8]);
            al[rt] = *(const bf16x8*)(&Xl[(wr * 32 + rt * 16 + m) * 40 + q * 8]);
        }
#pragma unroll
        for (int ct = 0; ct < 8; ct++) {
            bf16x8 bh = *(const bf16x8*)(&Wh[(wc * 128 + ct * 16 + m) * 40 + q * 8]);
            bf16x8 bl = *(const bf16x8*)(&Wl[(wc * 128 + ct * 16 + m) * 40 + q * 8]);
#pragma unroll
            for (int rt = 0; rt < 2; rt++) {
                acc[rt * 8 + ct] = __builtin_amdgcn_mfma_f32_16x16x32_bf16(ah[rt], bh, acc[rt * 8 + ct], 0, 0, 0);
                acc[rt * 8 + ct] = __builtin_amdgcn_mfma_f32_16x16x32_bf16(ah[rt], bl, acc[rt * 8 + ct], 0, 0, 0);
                acc[rt * 8 + ct] = __builtin_amdgcn_mfma_f32_16x16x32_bf16(al[rt], bh, acc[rt * 8 + ct], 0, 0, 0);
            }
        }
        __syncthreads();
    }

    if (z < 2) {
        i8_t* Dh = (z == 0) ? Q8h : K8h;
        i8_t* Dl = (z == 0) ? Q8l : K8l;
        float* sv = (z == 0) ? sqv : skv;
        float am[2][4];
#pragma unroll
        for (int rt = 0; rt < 2; rt++)
#pragma unroll
            for (int r = 0; r < 4; r++) am[rt][r] = 0.f;
#pragma unroll
        for (int ct = 0; ct < 8; ct++)
#pragma unroll
            for (int rt = 0; rt < 2; rt++)
#pragma unroll
                for (int r = 0; r < 4; r++)
                    am[rt][r] = fmaxf(am[rt][r], fabsf(acc[rt * 8 + ct][r]));
#pragma unroll
        for (int off = 1; off < 16; off <<= 1)
#pragma unroll
            for (int rt = 0; rt < 2; rt++)
#pragma unroll
                for (int r = 0; r < 4; r++)
                    am[rt][r] = fmaxf(am[rt][r], __shfl_xor(am[rt][r], off, 64));
        if (m == 0) {
#pragma unroll
            for (int rt = 0; rt < 2; rt++)
#pragma unroll
                for (int r = 0; r < 4; r++)
                    amS[wc * 64 + wr * 32 + rt * 16 + q * 4 + r] = am[rt][r];
        }
        __syncthreads();
        float sc[2][4], inv[2][4];
#pragma unroll
        for (int rt = 0; rt < 2; rt++)
#pragma unroll
            for (int r = 0; r < 4; r++) {
                int row = wr * 32 + rt * 16 + q * 4 + r;
                float a = fmaxf(amS[row], amS[64 + row]);
                sc[rt][r]  = (a > 0.f) ? a * (1.f / 127.f) : 1.f;
                inv[rt][r] = (a > 0.f) ? 127.f / a : 0.f;
            }
#pragma unroll
        for (int ct = 0; ct < 8; ct++)
#pragma unroll
            for (int rt = 0; rt < 2; rt++)
#pragma unroll
                for (int r = 0; r < 4; r++) {
                    float vq = acc[rt * 8 + ct][r] * inv[rt][r];
                    float qh = rintf(vq);
                    float ql = fminf(fmaxf(rintf((vq - qh) * 256.f), -127.f), 127.f);
                    int offo = (row0 + wr * 32 + rt * 16 + q * 4 + r) * 256 +
                               wc * 128 + ct * 16 + m;
                    Dh[offo] = (i8_t)(int)qh;
                    Dl[offo] = (i8_t)(int)ql;
                }
        if (m == 0 && wc == 0) {
#pragma unroll
            for (int rt = 0; rt < 2; rt++)
#pragma unroll
                for (int r = 0; r < 4; r++)
                    sv[row0 + wr * 32 + rt * 16 + q * 4 + r] = sc[rt][r];
        }
    } else {
        char* VtB = SM;
#pragma unroll
        for (int ct = 0; ct < 8; ct++)
#pragma unroll
            for (int rt = 0; rt < 2; rt++) {
                int d = wc * 128 + ct * 16 + m;
                int n0 = wr * 32 + rt * 16 + q * 4;
                bf16x4 v4;
#pragma unroll
                for (int r = 0; r < 4; r++) v4[r] = (bf16_t)acc[rt * 8 + ct][r];
                *(bf16x4*)(VtB + d * 136 + n0 * 2) = v4;
            }
        __syncthreads();
        const int bb = row0 >> 11;
        const int nbase = row0 & 2047;
        bf16_t* Hrow = H3t + (size_t)bb * 256 * 2048 + nbase;
#pragma unroll
        for (int it = 0; it < 16; it++) {
            int d = it * 16 + (tid >> 4);
            int c8 = tid & 15;
            bf16x4 v = *(const bf16x4*)(VtB + d * 136 + c8 * 8);
            *(bf16x4*)(Hrow + (size_t)d * 2048 + c8 * 4) = v;
        }
    }
}

// ---------------- kernel 3: flash attention (1-barrier dbuf + s_setprio) ----------------
// Round-14 attn kept verbatim (measured 92.9 us): dbuf K/V, 1 barrier/tile,
// defer-max THR=8, s_setprio(1) around QK and PV MFMA clusters.
#define K8SW(row, off) ((off) ^ (((row) & 7) << 4))        // K8 row stride 256B
#define VSW(row, off)  ((off) ^ ((((row) >> 1) & 3) << 4)) // Vl/Pl row stride 64B
__global__ __launch_bounds__(256, 2) void attn_kernel(
    const i8_t* __restrict__ Q8h, const i8_t* __restrict__ Q8l,
    const float* __restrict__ sqv,
    const i8_t* __restrict__ K8h, const i8_t* __restrict__ K8l,
    const float* __restrict__ skv,
    const bf16_t* __restrict__ H3t, const unsigned* __restrict__ adjbits,
    bf16_t* __restrict__ Opart, float* __restrict__ mpart, float* __restrict__ lpart,
    int klen) {
    __shared__ i8_t K8[2][2][32 * 256];   // [buf][hi/lo] (32 KB)
    __shared__ bf16_t Vl[2][256 * 32];    // [buf] (32 KB)
    __shared__ bf16_t Pl[4][16 * 32];     // per-wave P round-trip (4 KB)

    const int nwg = (int)(gridDim.x * gridDim.y * gridDim.z);   // 32*8*S
    const int wgid = (int)(blockIdx.x + (blockIdx.y << 5) + (blockIdx.z << 8));
    const int nid = (wgid & 7) * (nwg >> 3) + (wgid >> 3);
    const int qb = nid & 31;
    const int b  = (nid >> 5) & 7;
    const int kz = nid >> 8;

    const int q0 = qb * 64;
    const int tid = threadIdx.x;
    const int w = tid >> 6, lane = tid & 63;
    const int m = lane & 15, q = lane >> 4;

    char* PlB = (char*)&Pl[w][0];

    const i8_t* qrh = Q8h + (size_t)(b * 2048 + q0 + w * 16 + m) * 256;
    const i8_t* qrl = Q8l + (size_t)(b * 2048 + q0 + w * 16 + m) * 256;
    intx4 qh8[4], ql8[4];
#pragma unroll
    for (int ck = 0; ck < 4; ck++) {
        qh8[ck] = *(const intx4*)(qrh + ck * 64 + q * 16);
        ql8[ck] = *(const intx4*)(qrl + ck * 64 + q * 16);
    }
    float sq4[4];
#pragma unroll
    for (int r = 0; r < 4; r++) sq4[r] = sqv[b * 2048 + q0 + w * 16 + q * 4 + r];

    bf16x8 vones;
#pragma unroll
    for (int i = 0; i < 8; i++) vones[i] = (bf16_t)1.0f;

    float m_run[4];
#pragma unroll
    for (int r = 0; r < 4; r++) m_run[r] = -3.0e38f;
    floatx4 l_acc = (floatx4){0.f, 0.f, 0.f, 0.f};
    floatx4 o[16];
#pragma unroll
    for (int i = 0; i < 16; i++) o[i] = (floatx4){0.f, 0.f, 0.f, 0.f};

    const unsigned* bitrow[4];
#pragma unroll
    for (int r = 0; r < 4; r++)
        bitrow[r] = adjbits + (size_t)(q0 + w * 16 + q * 4 + r) * 64;

    intx4 rkh[2], rkl[2];
    bf16x8 rvv[4];
    float skt[2], skn[2];
    const int kbeg = kz * klen, kend = kbeg + klen;

#pragma unroll
    for (int i = 0; i < 2; i++) {
        int ci = i * 256 + tid;
        int kr = ci >> 4, cb = (ci & 15) * 16;
        rkh[i] = *(const intx4*)(K8h + (size_t)(b * 2048 + kbeg + kr) * 256 + cb);
        rkl[i] = *(const intx4*)(K8l + (size_t)(b * 2048 + kbeg + kr) * 256 + cb);
    }
#pragma unroll
    for (int i = 0; i < 4; i++) {
        int ci = i * 256 + tid;
        int d = ci >> 2, k8 = (ci & 3) * 8;
        rvv[i] = *(const bf16x8*)(H3t + (size_t)(b * 256 + d) * 2048 + kbeg + k8);
    }
    skt[0] = skv[b * 2048 + kbeg + m];
    skt[1] = skv[b * 2048 + kbeg + 16 + m];

    int kbuf = 0;
    for (int k0 = kbeg; k0 < kend; k0 += 32) {
        char* KB0 = (char*)&K8[kbuf][0][0];
        char* KB1 = (char*)&K8[kbuf][1][0];
        char* VB  = (char*)&Vl[kbuf][0];
#pragma unroll
        for (int i = 0; i < 2; i++) {
            int ci = i * 256 + tid;
            int kr = ci >> 4, cb = (ci & 15) * 16;
            *(intx4*)(KB0 + K8SW(kr, kr * 256 + cb)) = rkh[i];
            *(intx4*)(KB1 + K8SW(kr, kr * 256 + cb)) = rkl[i];
        }
#pragma unroll
        for (int i = 0; i < 4; i++) {
            int ci = i * 256 + tid;
            int d = ci >> 2, kb = (ci & 3) * 16;
            *(bf16x8*)(VB + VSW(d, d * 64 + kb)) = rvv[i];
        }
        __syncthreads();   // the ONLY barrier per tile

        if (k0 + 32 < kend) {
            int kn = k0 + 32;
#pragma unroll
            for (int i = 0; i < 2; i++) {
                int ci = i * 256 + tid;
                int kr = ci >> 4, cb = (ci & 15) * 16;
                rkh[i] = *(const intx4*)(K8h + (size_t)(b * 2048 + kn + kr) * 256 + cb);
                rkl[i] = *(const intx4*)(K8l + (size_t)(b * 2048 + kn + kr) * 256 + cb);
            }
#pragma unroll
            for (int i = 0; i < 4; i++) {
                int ci = i * 256 + tid;
                int d = ci >> 2, k8 = (ci & 3) * 8;
                rvv[i] = *(const bf16x8*)(H3t + (size_t)(b * 256 + d) * 2048 + kn + k8);
            }
            skn[0] = skv[b * 2048 + kn + m];
            skn[1] = skv[b * 2048 + kn + 16 + m];
        }

        // ---- S = Q K^T in i8 hi/lo ----
        float s[2][4];
        __builtin_amdgcn_s_setprio(1);
#pragma unroll
        for (int t = 0; t < 2; t++) {
            intx4 ch = {0, 0, 0, 0}, cm = {0, 0, 0, 0};
            const int row = t * 16 + m;
#pragma unroll
            for (int ck = 0; ck < 4; ck++) {
                const int cb2 = ck * 64 + q * 16;
                intx4 kh = *(const intx4*)(KB0 + K8SW(row, row * 256 + cb2));
                intx4 kl = *(const intx4*)(KB1 + K8SW(row, row * 256 + cb2));
                ch = __builtin_amdgcn_mfma_i32_16x16x64_i8(qh8[ck], kh, ch, 0, 0, 0);
                cm = __builtin_amdgcn_mfma_i32_16x16x64_i8(qh8[ck], kl, cm, 0, 0, 0);
                cm = __builtin_amdgcn_mfma_i32_16x16x64_i8(ql8[ck], kh, cm, 0, 0, 0);
            }
#pragma unroll
            for (int r = 0; r < 4; r++)
                s[t][r] = fmaf((float)cm[r], 0.00390625f, (float)ch[r]) * (sq4[r] * skt[t]);
        }
        __builtin_amdgcn_s_setprio(0);

        // ---- leaky-relu + mask + tile row max ----
        unsigned aw[4];
#pragma unroll
        for (int r = 0; r < 4; r++) aw[r] = bitrow[r][k0 >> 5];
        float p[2][4], tmax[4];
#pragma unroll
        for (int r = 0; r < 4; r++) tmax[r] = -3.0e38f;
#pragma unroll
        for (int t = 0; t < 2; t++)
#pragma unroll
            for (int r = 0; r < 4; r++) {
                float v = s[t][r];
                v = (v > 0.f) ? v : 0.2f * v;
                v = ((aw[r] >> (t * 16 + m)) & 1u) ? v : -1.0e12f;
                p[t][r] = v;
                tmax[r] = fmaxf(tmax[r], v);
            }
#pragma unroll
        for (int off = 1; off < 16; off <<= 1)
#pragma unroll
            for (int r = 0; r < 4; r++)
                tmax[r] = fmaxf(tmax[r], __shfl_xor(tmax[r], off, 64));

        // ---- defer-max (THR=8) ----
        int rise = 0;
#pragma unroll
        for (int r = 0; r < 4; r++)
            rise |= (tmax[r] > m_run[r] + 8.f);
        if (__any(rise)) {
#pragma unroll
            for (int r = 0; r < 4; r++) {
                float mnew = fmaxf(m_run[r], tmax[r]);
                float alpha = __expf(m_run[r] - mnew);
                m_run[r] = mnew;
                l_acc[r] *= alpha;
#pragma unroll
                for (int nt = 0; nt < 16; nt++) o[nt][r] *= alpha;
            }
        }
#pragma unroll
        for (int t = 0; t < 2; t++)
#pragma unroll
            for (int r = 0; r < 4; r++)
                p[t][r] = __expf(p[t][r] - m_run[r]);

        // ---- P: C-layout -> per-wave LDS -> A-layout (same wave, no barrier) ----
#pragma unroll
        for (int t = 0; t < 2; t++)
#pragma unroll
            for (int r = 0; r < 4; r++) {
                int row = q * 4 + r;
                *(bf16_t*)(PlB + VSW(row, row * 64 + (t * 16 + m) * 2)) = (bf16_t)p[t][r];
            }
        bf16x8 pf = *(const bf16x8*)(PlB + VSW(m, m * 64 + q * 16));

        // ---- l += P @ ones; O += P @ V ----
        __builtin_amdgcn_s_setprio(1);
        l_acc = __builtin_amdgcn_mfma_f32_16x16x32_bf16(pf, vones, l_acc, 0, 0, 0);
#pragma unroll
        for (int nt = 0; nt < 16; nt++) {
            const int vr = nt * 16 + m;
            bf16x8 vf = *(const bf16x8*)(VB + VSW(vr, vr * 64 + q * 16));
            o[nt] = __builtin_amdgcn_mfma_f32_16x16x32_bf16(pf, vf, o[nt], 0, 0, 0);
        }
        __builtin_amdgcn_s_setprio(0);
        skt[0] = skn[0];
        skt[1] = skn[1];
        kbuf ^= 1;
    }

    const int rowg = kz * 16384 + b * 2048 + q0 + w * 16 + q * 4;
#pragma unroll
    for (int nt = 0; nt < 16; nt++)
#pragma unroll
        for (int r = 0; r < 4; r++)
            Opart[(size_t)(rowg + r) * 256 + nt * 16 + m] = (bf16_t)o[nt][r];
    if (m == 0) {
#pragma unroll
        for (int r = 0; r < 4; r++) {
            mpart[rowg + r] = m_run[r];
            lpart[rowg + r] = l_acc[r];
        }
    }
}

// ---------------- kernel 4: merge splits + normalize + relu ----------------
__global__ __launch_bounds__(256) void merge_kernel(
    const bf16_t* __restrict__ Opart, const float* __restrict__ mpart,
    const float* __restrict__ lpart, float* __restrict__ out, int S) {
    int gid = blockIdx.x * 256 + threadIdx.x;
    int row = gid >> 6, c4 = (gid & 63) * 4;
    float M = -3.0e38f;
    for (int s = 0; s < S; s++) M = fmaxf(M, mpart[s * 16384 + row]);
    float denom = 0.f;
    float4 acc = make_float4(0.f, 0.f, 0.f, 0.f);
    for (int s = 0; s < S; s++) {
        float sc = __expf(mpart[s * 16384 + row] - M);
        denom += lpart[s * 16384 + row] * sc;
        bf16x4 v = *(const bf16x4*)(Opart + ((size_t)(s * 16384 + row)) * 256 + c4);
        acc.x += (float)v[0] * sc; acc.y += (float)v[1] * sc;
        acc.z += (float)v[2] * sc; acc.w += (float)v[3] * sc;
    }
    float inv = 1.f / denom;
    float4 r;
    r.x = fmaxf(acc.x * inv, 0.f);
    r.y = fmaxf(acc.y * inv, 0.f);
    r.z = fmaxf(acc.z * inv, 0.f);
    r.w = fmaxf(acc.w * inv, 0.f);
    *(float4*)(out + (size_t)row * 256 + c4) = r;
}

extern "C" void kernel_launch(void* const* d_in, const int* in_sizes, int n_in,
                              void* d_out, int out_size, void* d_ws, size_t ws_size,
                              hipStream_t stream) {
    const float* X   = (const float*)d_in[0];
    const int*   adj = (const int*)d_in[1];
    const float* W1  = (const float*)d_in[2];
    const float* W2  = (const float*)d_in[3];
    const float* W3  = (const float*)d_in[4];
    float* out = (float*)d_out;

    char* ws = (char*)d_ws;
    i8_t* Q8h = (i8_t*)(ws + ((size_t)0 << 20));    // 16384*256 = 4 MB each
    i8_t* Q8l = (i8_t*)(ws + ((size_t)4 << 20));
    i8_t* K8h = (i8_t*)(ws + ((size_t)8 << 20));
    i8_t* K8l = (i8_t*)(ws + ((size_t)12 << 20));
    bf16_t* H3t = (bf16_t*)(ws + ((size_t)16 << 20));   // 8 MB
    float* sqv = (float*)(ws + ((size_t)24 << 20));     // 64 KB
    float* skv = (float*)(ws + ((size_t)24 << 20) + 65536);
    size_t wt0 = ((size_t)24 << 20) + 131072;
    bf16_t* Wthi = (bf16_t*)(ws + wt0);                 // 393,216 B
    bf16_t* Wtlo = (bf16_t*)(ws + wt0 + 393216);        // 393,216 B
    float* mpart = (float*)(ws + wt0);                  // overlays Wt (dead after proj)
    float* lpart = (float*)(ws + wt0 + 131072);
    unsigned* adjb = (unsigned*)(ws + wt0 + 786432);    // 524,288 B
    size_t opart_off = wt0 + 786432 + 524288;
    const size_t need2 = opart_off + (size_t)2 * 16384 * 256 * 2;  // bf16 Opart, ~43 MB

    int S = (ws_size >= need2) ? 2 : 1;
    bf16_t* Opart = (bf16_t*)(ws + opart_off);

    wtrans_kernel<<<dim3(4, 4, 3), 256, 0, stream>>>(W1, W2, W3, Wthi, Wtlo);
    projadj_kernel<<<1280, 256, 0, stream>>>(X, Wthi, Wtlo,
                                             Q8h, Q8l, sqv, K8h, K8l, skv, H3t,
                                             adj, adjb);
    attn_kernel<<<dim3(32, 8, S), 256, 0, stream>>>(Q8h, Q8l, sqv, K8h, K8l, skv,
                                                    H3t, adjb, Opart, mpart, lpart,
                                                    2048 / S);
    merge_kernel<<<4096, 256, 0, stream>>>(Opart, mpart, lpart, out, S);
}